// Round 3
// baseline (121.378 us; speedup 1.0000x reference)
//
#include <hip/hip_runtime.h>
#include <hip/hip_bf16.h>

typedef unsigned short u16;
typedef __attribute__((ext_vector_type(8))) __bf16 bf16x8;
typedef __attribute__((ext_vector_type(4))) float f32x4;

#define B_SZ 4096
#define D_SZ 1024
#define MARGIN 0.2f

__device__ __forceinline__ u16 f2bf(float x) {
  __hip_bfloat16 h = __float2bfloat16(x);
  u16 r; __builtin_memcpy(&r, &h, 2); return r;
}

// ---------------- normalize + cast to bf16 + diag ----------------
__global__ void norm_diag_kernel(const float* __restrict__ im,
                                 const float* __restrict__ tx,
                                 u16* __restrict__ imn,
                                 u16* __restrict__ txn,
                                 float* __restrict__ diag) {
  const int row = blockIdx.x;
  const int t = threadIdx.x;
  const size_t base = (size_t)row * D_SZ;
  float4 vi = reinterpret_cast<const float4*>(im + base)[t];
  float4 vt = reinterpret_cast<const float4*>(tx + base)[t];
  float ssi = vi.x * vi.x + vi.y * vi.y + vi.z * vi.z + vi.w * vi.w;
  float sst = vt.x * vt.x + vt.y * vt.y + vt.z * vt.z + vt.w * vt.w;
  float dot = vi.x * vt.x + vi.y * vt.y + vi.z * vt.z + vi.w * vt.w;
#pragma unroll
  for (int off = 32; off > 0; off >>= 1) {
    ssi += __shfl_down(ssi, off, 64);
    sst += __shfl_down(sst, off, 64);
    dot += __shfl_down(dot, off, 64);
  }
  __shared__ float w[3][4];
  if ((t & 63) == 0) { int wi = t >> 6; w[0][wi] = ssi; w[1][wi] = sst; w[2][wi] = dot; }
  __syncthreads();
  const float tssi = (w[0][0] + w[0][1]) + (w[0][2] + w[0][3]);
  const float tsst = (w[1][0] + w[1][1]) + (w[1][2] + w[1][3]);
  const float tdot = (w[2][0] + w[2][1]) + (w[2][2] + w[2][3]);
  const float si = 1.0f / fmaxf(sqrtf(tssi), 1e-12f);
  const float st = 1.0f / fmaxf(sqrtf(tsst), 1e-12f);
  u16 oi[4] = { f2bf(vi.x * si), f2bf(vi.y * si), f2bf(vi.z * si), f2bf(vi.w * si) };
  u16 ot[4] = { f2bf(vt.x * st), f2bf(vt.y * st), f2bf(vt.z * st), f2bf(vt.w * st) };
  ushort4 pi, pt; __builtin_memcpy(&pi, oi, 8); __builtin_memcpy(&pt, ot, 8);
  reinterpret_cast<ushort4*>(imn + base)[t] = pi;
  reinterpret_cast<ushort4*>(txn + base)[t] = pt;
  if (t == 0) diag[row] = tdot * si * st;
}

// ---------------- GEMM (sim = imn @ txn^T) + fused hinge-loss epilogue ------
// 128x128 tile, BK=32, 4 waves (2x2), 4x4 frags of 16x16x32 bf16 MFMA.
// Round-3: triple-buffered LDS, prefetch depth 2, counted `s_waitcnt vmcnt(4)`
// + raw s_barrier per K-step (T3/T4 minimum recipe) — loads stay in flight
// across barriers; vmcnt(0) only in the final peeled step.
__device__ __forceinline__ void gload_lds16(const u16* g, u16* l) {
  __builtin_amdgcn_global_load_lds((__attribute__((address_space(1))) void*)g,
                                   (__attribute__((address_space(3))) void*)l,
                                   16, 0, 0);
}

__global__ __launch_bounds__(256) void gemm_loss_kernel(
    const u16* __restrict__ A,   // imn [4096][1024]
    const u16* __restrict__ Bt,  // txn [4096][1024]
    const float* __restrict__ diag,
    float* __restrict__ sim,     // d_out+1, row-major [4096][4096]
    float* __restrict__ loss) {
  __shared__ u16 As[3 * 128 * 32];   // 24 KB
  __shared__ u16 Bs[3 * 128 * 32];   // 24 KB
  const int tid = threadIdx.x;
  const int lane = tid & 63;
  const int wid = tid >> 6;

  // XCD-aware swizzle: 1024 blocks, 8 XCDs, 128 consecutive tiles per XCD.
  const int flat = blockIdx.y * gridDim.x + blockIdx.x;
  const int s = (flat & 7) * 128 + (flat >> 3);
  const int tm = (s >> 5) * 128;
  const int tn = (s & 31) * 128;

  const int wr = wid >> 1, wc = wid & 1;

  f32x4 acc[4][4] = {};

  // staging addresses (pre-swizzled global source; involution with read side)
  const int srow = lane >> 2;                       // 0..15
  const int sblk = (lane & 3) ^ (srow & 3);         // swizzled 8-elem block
  const u16* gA = A + (size_t)(tm + wid * 32 + srow) * D_SZ + sblk * 8;
  const u16* gB = Bt + (size_t)(tn + wid * 32 + srow) * D_SZ + sblk * 8;
  u16* lA = As + wid * 32 * 32;                     // wave-uniform LDS base
  u16* lB = Bs + wid * 32 * 32;

  const int ar = lane & 15;
  const int kx = ((lane >> 4) * 8) ^ ((lane & 3) * 8);  // swizzled k-offset

  auto stage = [&](int buf, int k0) {
    gload_lds16(gA + k0, lA + buf * 4096);
    gload_lds16(gA + k0 + 16 * D_SZ, lA + buf * 4096 + 512);
    gload_lds16(gB + k0, lB + buf * 4096);
    gload_lds16(gB + k0 + 16 * D_SZ, lB + buf * 4096 + 512);
  };
  auto compute = [&](const u16* Ab, const u16* Bb) {
    bf16x8 a[4], b[4];
#pragma unroll
    for (int m = 0; m < 4; m++)
      a[m] = *(const bf16x8*)&Ab[(wr * 64 + m * 16 + ar) * 32 + kx];
#pragma unroll
    for (int n = 0; n < 4; n++)
      b[n] = *(const bf16x8*)&Bb[(wc * 64 + n * 16 + ar) * 32 + kx];
#pragma unroll
    for (int m = 0; m < 4; m++)
#pragma unroll
      for (int n = 0; n < 4; n++)
        acc[m][n] = __builtin_amdgcn_mfma_f32_16x16x32_bf16(a[m], b[n], acc[m][n], 0, 0, 0);
  };

  // prologue: stages for K-tiles 0 and 1 (8 loads in flight)
  stage(0, 0);
  stage(1, 32);

  // main loop: 30 steps with counted vmcnt (never 0); stages tile t+2.
  for (int t = 0; t < 30; ++t) {
    asm volatile("s_waitcnt vmcnt(4)" ::: "memory");   // oldest 4 (tile t) done
    __builtin_amdgcn_s_barrier();                      // no vmcnt(0) drain here
    const int cb = t % 3;
    stage((t + 2) % 3, (t + 2) * 32);
    compute(As + cb * 4096, Bs + cb * 4096);
  }
  // t = 30 (buffer 0): tile 31's loads may still be in flight
  asm volatile("s_waitcnt vmcnt(4)" ::: "memory");
  __builtin_amdgcn_s_barrier();
  compute(As + 0 * 4096, Bs + 0 * 4096);
  // t = 31 (buffer 1): drain
  asm volatile("s_waitcnt vmcnt(0)" ::: "memory");
  __builtin_amdgcn_s_barrier();
  compute(As + 1 * 4096, Bs + 1 * 4096);

  // epilogue: write sim, accumulate hinge loss
  float dcs[4];
#pragma unroll
  for (int n = 0; n < 4; n++) dcs[n] = diag[tn + wc * 64 + n * 16 + ar];
  float lsum = 0.f;
#pragma unroll
  for (int m = 0; m < 4; m++) {
#pragma unroll
    for (int i = 0; i < 4; i++) {
      const int r = tm + wr * 64 + m * 16 + (lane >> 4) * 4 + i;
      const float dr = diag[r];
#pragma unroll
      for (int n = 0; n < 4; n++) {
        const int c = tn + wc * 64 + n * 16 + ar;
        const float s_ = acc[m][n][i];
        sim[(size_t)r * B_SZ + c] = s_;
        if (r != c)
          lsum += fmaxf(MARGIN + s_ - dr, 0.f) + fmaxf(MARGIN + s_ - dcs[n], 0.f);
      }
    }
  }
#pragma unroll
  for (int off = 32; off > 0; off >>= 1) lsum += __shfl_down(lsum, off, 64);
  if (lane == 0) atomicAdd(loss, lsum);
}

extern "C" void kernel_launch(void* const* d_in, const int* in_sizes, int n_in,
                              void* d_out, int out_size, void* d_ws, size_t ws_size,
                              hipStream_t stream) {
  const float* im = (const float*)d_in[0];
  const float* tx = (const float*)d_in[1];
  float* out = (float*)d_out;
  float* loss = out;        // output 0: scalar total_loss
  float* sim = out + 1;     // output 1: [4096][4096]

  u16* imn = (u16*)d_ws;
  u16* txn = imn + (size_t)B_SZ * D_SZ;
  float* diag = (float*)(txn + (size_t)B_SZ * D_SZ);

  hipMemsetAsync(d_out, 0, sizeof(float), stream);
  norm_diag_kernel<<<B_SZ, 256, 0, stream>>>(im, tx, imn, txn, diag);
  gemm_loss_kernel<<<dim3(B_SZ / 128, B_SZ / 128), 256, 0, stream>>>(imn, txn, diag, sim, loss);
}

// Round 4
// 85.380 us; speedup vs baseline: 1.4216x; 1.4216x over previous
//
#include <hip/hip_runtime.h>
#include <hip/hip_bf16.h>

typedef unsigned short u16;
typedef __attribute__((ext_vector_type(8))) __bf16 bf16x8;
typedef __attribute__((ext_vector_type(4))) float f32x4;

#define B_SZ 4096
#define D_SZ 1024
#define MARGIN 0.2f

__device__ __forceinline__ u16 f2bf(float x) {
  __hip_bfloat16 h = __float2bfloat16(x);
  u16 r; __builtin_memcpy(&r, &h, 2); return r;
}

// ---------------- normalize + cast to bf16 + diag ----------------
__global__ void norm_diag_kernel(const float* __restrict__ im,
                                 const float* __restrict__ tx,
                                 u16* __restrict__ imn,
                                 u16* __restrict__ txn,
                                 float* __restrict__ diag) {
  const int row = blockIdx.x;
  const int t = threadIdx.x;
  const size_t base = (size_t)row * D_SZ;
  float4 vi = reinterpret_cast<const float4*>(im + base)[t];
  float4 vt = reinterpret_cast<const float4*>(tx + base)[t];
  float ssi = vi.x * vi.x + vi.y * vi.y + vi.z * vi.z + vi.w * vi.w;
  float sst = vt.x * vt.x + vt.y * vt.y + vt.z * vt.z + vt.w * vt.w;
  float dot = vi.x * vt.x + vi.y * vt.y + vi.z * vt.z + vi.w * vt.w;
#pragma unroll
  for (int off = 32; off > 0; off >>= 1) {
    ssi += __shfl_down(ssi, off, 64);
    sst += __shfl_down(sst, off, 64);
    dot += __shfl_down(dot, off, 64);
  }
  __shared__ float w[3][4];
  if ((t & 63) == 0) { int wi = t >> 6; w[0][wi] = ssi; w[1][wi] = sst; w[2][wi] = dot; }
  __syncthreads();
  const float tssi = (w[0][0] + w[0][1]) + (w[0][2] + w[0][3]);
  const float tsst = (w[1][0] + w[1][1]) + (w[1][2] + w[1][3]);
  const float tdot = (w[2][0] + w[2][1]) + (w[2][2] + w[2][3]);
  const float si = 1.0f / fmaxf(sqrtf(tssi), 1e-12f);
  const float st = 1.0f / fmaxf(sqrtf(tsst), 1e-12f);
  u16 oi[4] = { f2bf(vi.x * si), f2bf(vi.y * si), f2bf(vi.z * si), f2bf(vi.w * si) };
  u16 ot[4] = { f2bf(vt.x * st), f2bf(vt.y * st), f2bf(vt.z * st), f2bf(vt.w * st) };
  ushort4 pi, pt; __builtin_memcpy(&pi, oi, 8); __builtin_memcpy(&pt, ot, 8);
  reinterpret_cast<ushort4*>(imn + base)[t] = pi;
  reinterpret_cast<ushort4*>(txn + base)[t] = pt;
  if (t == 0) diag[row] = tdot * si * st;
}

// ---------------- 256x256 8-phase GEMM + fused hinge-loss epilogue ----------
// BM=BN=256, BK=64, 8 waves (2M x 4N), 512 threads, 128 KiB LDS.
// LDS regions (16 KiB each): [buf][mat A/B][K-half], each 256 rows x 32 cols.
// Clusters: C1=ks0*n01, C2=ks0*n23, C3=ks1*n01, C4=ks1*n23 (16 MFMA each).
// Stage stream (1 region/phase): PhA:(t+1).B-K1, PhB:(t+2).A-K0,
// PhC:(t+2).B-K0, PhD:(t+2).A-K1.  Gate vmcnt(6) once per K-tile at PhD.
// XOR swizzle slot ^= (r&3)^((r>>2)&3) applied on stage source AND ds_read.
__device__ __forceinline__ void gload_lds16(const u16* g, u16* l) {
  __builtin_amdgcn_global_load_lds((__attribute__((address_space(1))) void*)g,
                                   (__attribute__((address_space(3))) void*)l,
                                   16, 0, 0);
}

__global__ __launch_bounds__(512, 2) void gemm_loss_kernel(
    const u16* __restrict__ A,   // imn [4096][1024]
    const u16* __restrict__ Bt,  // txn [4096][1024]
    const float* __restrict__ diag,
    float* __restrict__ sim,     // d_out+1, row-major [4096][4096]
    float* __restrict__ loss) {
  __shared__ u16 sm[65536];      // 128 KiB: ((buf<<2)|(mat<<1)|kh) * 8192

  const int tid = threadIdx.x;
  const int l = tid & 63;
  const int w = tid >> 6;        // wave 0..7
  const int wr = w >> 2;         // 0..1  (M half)
  const int wc = w & 3;          // 0..3  (N quarter)
  const int ar = l & 15;
  const int arh = l >> 4;        // 0..3

  // XCD-aware bijective swizzle: 256 blocks, 8 XCDs, 32 consecutive per XCD.
  const int bid = blockIdx.x;
  const int s = (bid & 7) * 32 + (bid >> 3);
  const int tm = (s >> 4) * 256;
  const int tn = (s & 15) * 256;

  f32x4 acc[8][4] = {};

  // ---- staging addressing (pre-swizzled global source) ----
  const int r0 = w * 16 + (l >> 2);                       // rows 0..127 (j=0)
  const int c16s = (l & 3) ^ ((l >> 2) & 3) ^ ((l >> 4) & 3);
  const u16* gA0 = A + (size_t)(tm + r0) * D_SZ + c16s * 8;
  const u16* gA1 = A + (size_t)(tm + 128 + r0) * D_SZ + c16s * 8;
  const u16* gB0 = Bt + (size_t)(tn + r0) * D_SZ + c16s * 8;
  const u16* gB1 = Bt + (size_t)(tn + 128 + r0) * D_SZ + c16s * 8;

  auto SA = [&](int kt, int kh) {                          // stage A K-half
    u16* d = sm + ((((kt & 1) << 2) | 0 | kh) * 8192) + w * 512;
    const int go = kt * 64 + kh * 32;
    gload_lds16(gA0 + go, d);
    gload_lds16(gA1 + go, d + 4096);
  };
  auto SB = [&](int kt, int kh) {                          // stage B K-half
    u16* d = sm + ((((kt & 1) << 2) | 2 | kh) * 8192) + w * 512;
    const int go = kt * 64 + kh * 32;
    gload_lds16(gB0 + go, d);
    gload_lds16(gB1 + go, d + 4096);
  };

  // ---- read addressing (swizzled, same involution) ----
  const int fA = (ar & 3) ^ ((ar >> 2) & 3);
  const int sl = (arh ^ fA) * 8;                           // element offset
  const int aoff = (wr * 128 + ar) * 32 + sl;
  const int boff = (wc * 64 + ar) * 32 + sl;

  bf16x8 a[8], b01[2], b23[2];
  auto LDA = [&](int buf, int ks) {                        // 8 reads
    const u16* base = sm + (((buf << 2) | 0 | ks) * 8192) + aoff;
#pragma unroll
    for (int m = 0; m < 8; m++) a[m] = *(const bf16x8*)&base[m * 512];
  };
  auto LDB = [&](int buf, int ks, int nb, bf16x8* bb) {    // 2 reads
    const u16* base = sm + (((buf << 2) | 2 | ks) * 8192) + boff;
#pragma unroll
    for (int n = 0; n < 2; n++) bb[n] = *(const bf16x8*)&base[(nb + n) * 512];
  };
  auto CL = [&](bf16x8* bb, int nbase) {                   // 16 MFMA
    __builtin_amdgcn_s_setprio(1);
#pragma unroll
    for (int m = 0; m < 8; m++)
#pragma unroll
      for (int n = 0; n < 2; n++)
        acc[m][nbase + n] =
            __builtin_amdgcn_mfma_f32_16x16x32_bf16(a[m], bb[n], acc[m][nbase + n], 0, 0, 0);
    __builtin_amdgcn_s_setprio(0);
  };

#define BAR() __builtin_amdgcn_s_barrier()
#define LGKM0() asm volatile("s_waitcnt lgkmcnt(0)" ::: "memory")

  // ---- prologue: 7 region-stages (14 loads) ----
  SA(0, 0); SB(0, 0); SA(0, 1); SB(0, 1);   // K-tile 0 complete
  SA(1, 0); SB(1, 0); SA(1, 1);             // K-tile 1 (B-K1 staged in PhA(0))
  asm volatile("s_waitcnt vmcnt(6)" ::: "memory");  // K0's 4 stages landed
  BAR();

  // ---- main loop: K-tiles 0..13 ----
  for (int t = 0; t < 14; ++t) {
    const int buf = t & 1;
    // PhA: C1 = ks0 x n01
    LDA(buf, 0); LDB(buf, 0, 0, b01);
    SB(t + 1, 1);
    asm volatile("s_waitcnt lgkmcnt(8)" ::: "memory");
    BAR(); LGKM0();
    CL(b01, 0);
    BAR();
    // PhB: C2 = ks0 x n23
    LDB(buf, 0, 2, b23);
    SA(t + 2, 0);
    BAR(); LGKM0();
    CL(b23, 2);
    BAR();
    // PhC: C3 = ks1 x n01
    LDA(buf, 1); LDB(buf, 1, 0, b01);
    SB(t + 2, 0);
    asm volatile("s_waitcnt lgkmcnt(8)" ::: "memory");
    BAR(); LGKM0();
    CL(b01, 0);
    BAR();
    // PhD: C4 = ks1 x n23  (+ once-per-K-tile vmcnt gate)
    LDB(buf, 1, 2, b23);
    SA(t + 2, 1);
    asm volatile("s_waitcnt vmcnt(6)" ::: "memory");
    BAR(); LGKM0();
    CL(b23, 2);
    BAR();
  }

  // ---- epilogue K-tile 14 (buf 0): last stage + drain gate ----
  {
    const int buf = 0;
    LDA(buf, 0); LDB(buf, 0, 0, b01);
    SB(15, 1);                                   // final stage
    BAR(); LGKM0();
    CL(b01, 0);
    BAR();
    LDB(buf, 0, 2, b23);
    BAR(); LGKM0();
    CL(b23, 2);
    BAR();
    LDA(buf, 1); LDB(buf, 1, 0, b01);
    BAR(); LGKM0();
    CL(b01, 0);
    BAR();
    LDB(buf, 1, 2, b23);
    asm volatile("s_waitcnt vmcnt(0)" ::: "memory");  // all stages landed
    BAR(); LGKM0();
    CL(b23, 2);
    BAR();
  }
  // ---- epilogue K-tile 15 (buf 1): no stages, no barriers needed ----
  {
    const int buf = 1;
    LDA(buf, 0); LDB(buf, 0, 0, b01); LGKM0(); CL(b01, 0);
    LDB(buf, 0, 2, b23);              LGKM0(); CL(b23, 2);
    LDA(buf, 1); LDB(buf, 1, 0, b01); LGKM0(); CL(b01, 0);
    LDB(buf, 1, 2, b23);              LGKM0(); CL(b23, 2);
  }

  // ---- C-write + hinge loss ----
  float dcs[4];
#pragma unroll
  for (int n = 0; n < 4; n++) dcs[n] = diag[tn + wc * 64 + n * 16 + ar];
  float lsum = 0.f;
#pragma unroll
  for (int m = 0; m < 8; m++) {
#pragma unroll
    for (int i = 0; i < 4; i++) {
      const int r = tm + wr * 128 + m * 16 + arh * 4 + i;
      const float dr = diag[r];
#pragma unroll
      for (int n = 0; n < 4; n++) {
        const int c = tn + wc * 64 + n * 16 + ar;
        const float s_ = acc[m][n][i];
        sim[(size_t)r * B_SZ + c] = s_;
        if (r != c)
          lsum += fmaxf(MARGIN + s_ - dr, 0.f) + fmaxf(MARGIN + s_ - dcs[n], 0.f);
      }
    }
  }
#pragma unroll
  for (int off = 32; off > 0; off >>= 1) lsum += __shfl_down(lsum, off, 64);
  if (l == 0) atomicAdd(loss, lsum);
#undef BAR
#undef LGKM0
}

extern "C" void kernel_launch(void* const* d_in, const int* in_sizes, int n_in,
                              void* d_out, int out_size, void* d_ws, size_t ws_size,
                              hipStream_t stream) {
  const float* im = (const float*)d_in[0];
  const float* tx = (const float*)d_in[1];
  float* out = (float*)d_out;
  float* loss = out;        // output 0: scalar total_loss
  float* sim = out + 1;     // output 1: [4096][4096]

  u16* imn = (u16*)d_ws;
  u16* txn = imn + (size_t)B_SZ * D_SZ;
  float* diag = (float*)(txn + (size_t)B_SZ * D_SZ);

  hipMemsetAsync(d_out, 0, sizeof(float), stream);
  norm_diag_kernel<<<B_SZ, 256, 0, stream>>>(im, tx, imn, txn, diag);
  gemm_loss_kernel<<<(B_SZ / 256) * (B_SZ / 256), 512, 0, stream>>>(imn, txn, diag, sim, loss);
}

// Round 5
// 83.264 us; speedup vs baseline: 1.4578x; 1.0254x over previous
//
#include <hip/hip_runtime.h>
#include <hip/hip_bf16.h>

typedef unsigned short u16;
typedef __attribute__((ext_vector_type(8))) __bf16 bf16x8;
typedef __attribute__((ext_vector_type(4))) float f32x4;

#define B_SZ 4096
#define D_SZ 1024
#define MARGIN 0.2f

__device__ __forceinline__ u16 f2bf(float x) {
  __hip_bfloat16 h = __float2bfloat16(x);
  u16 r; __builtin_memcpy(&r, &h, 2); return r;
}

// ---------------- normalize + cast to bf16 + diag ----------------
__global__ void norm_diag_kernel(const float* __restrict__ im,
                                 const float* __restrict__ tx,
                                 u16* __restrict__ imn,
                                 u16* __restrict__ txn,
                                 float* __restrict__ diag) {
  const int row = blockIdx.x;
  const int t = threadIdx.x;
  const size_t base = (size_t)row * D_SZ;
  float4 vi = reinterpret_cast<const float4*>(im + base)[t];
  float4 vt = reinterpret_cast<const float4*>(tx + base)[t];
  float ssi = vi.x * vi.x + vi.y * vi.y + vi.z * vi.z + vi.w * vi.w;
  float sst = vt.x * vt.x + vt.y * vt.y + vt.z * vt.z + vt.w * vt.w;
  float dot = vi.x * vt.x + vi.y * vt.y + vi.z * vt.z + vi.w * vt.w;
#pragma unroll
  for (int off = 32; off > 0; off >>= 1) {
    ssi += __shfl_down(ssi, off, 64);
    sst += __shfl_down(sst, off, 64);
    dot += __shfl_down(dot, off, 64);
  }
  __shared__ float w[3][4];
  if ((t & 63) == 0) { int wi = t >> 6; w[0][wi] = ssi; w[1][wi] = sst; w[2][wi] = dot; }
  __syncthreads();
  const float tssi = (w[0][0] + w[0][1]) + (w[0][2] + w[0][3]);
  const float tsst = (w[1][0] + w[1][1]) + (w[1][2] + w[1][3]);
  const float tdot = (w[2][0] + w[2][1]) + (w[2][2] + w[2][3]);
  const float si = 1.0f / fmaxf(sqrtf(tssi), 1e-12f);
  const float st = 1.0f / fmaxf(sqrtf(tsst), 1e-12f);
  u16 oi[4] = { f2bf(vi.x * si), f2bf(vi.y * si), f2bf(vi.z * si), f2bf(vi.w * si) };
  u16 ot[4] = { f2bf(vt.x * st), f2bf(vt.y * st), f2bf(vt.z * st), f2bf(vt.w * st) };
  ushort4 pi, pt; __builtin_memcpy(&pi, oi, 8); __builtin_memcpy(&pt, ot, 8);
  reinterpret_cast<ushort4*>(imn + base)[t] = pi;
  reinterpret_cast<ushort4*>(txn + base)[t] = pt;
  if (t == 0) diag[row] = tdot * si * st;
}

// ---------------- 256x256 8-phase GEMM + fused hinge-loss epilogue ----------
// BM=BN=256, BK=64, 8 waves (2M x 4N), 512 threads, 128 KiB LDS.
// Round-5: ds_reads software-pipelined ONE PHASE AHEAD (reads for cluster i+1
// drain under MFMA of cluster i), lgkmcnt(#issued-this-phase) instead of
// lgkmcnt(0), and ONE barrier per phase (ledger-verified: every region's last
// read is lgkm-waited exactly one phase before the stage that overwrites it).
// Stage stream unchanged: C1:SB(t+1,1) C2:SA(t+2,0) C3:SB(t+2,0) C4:SA(t+2,1);
// vmcnt(6) gate once per K-tile at C4 (before C4's prefetch reads).
__device__ __forceinline__ void gload_lds16(const u16* g, u16* l) {
  __builtin_amdgcn_global_load_lds((__attribute__((address_space(1))) void*)g,
                                   (__attribute__((address_space(3))) void*)l,
                                   16, 0, 0);
}

__global__ __launch_bounds__(512, 2) void gemm_loss_kernel(
    const u16* __restrict__ A,   // imn [4096][1024]
    const u16* __restrict__ Bt,  // txn [4096][1024]
    const float* __restrict__ diag,
    float* __restrict__ sim,     // d_out+1, row-major [4096][4096]
    float* __restrict__ loss) {
  __shared__ u16 sm[65536];      // 128 KiB: ((buf<<2)|(mat<<1)|kh) * 8192

  const int tid = threadIdx.x;
  const int l = tid & 63;
  const int w = tid >> 6;        // wave 0..7
  const int wr = w >> 2;         // 0..1  (M half)
  const int wc = w & 3;          // 0..3  (N quarter)
  const int ar = l & 15;
  const int arh = l >> 4;        // 0..3

  // XCD-aware bijective swizzle: 256 blocks, 8 XCDs, 32 consecutive per XCD.
  const int bid = blockIdx.x;
  const int s = (bid & 7) * 32 + (bid >> 3);
  const int tm = (s >> 4) * 256;
  const int tn = (s & 15) * 256;

  f32x4 acc[8][4] = {};

  // ---- staging addressing (pre-swizzled global source) ----
  const int r0 = w * 16 + (l >> 2);                       // rows 0..127
  const int c16s = (l & 3) ^ ((l >> 2) & 3) ^ ((l >> 4) & 3);
  const u16* gA0 = A + (size_t)(tm + r0) * D_SZ + c16s * 8;
  const u16* gA1 = A + (size_t)(tm + 128 + r0) * D_SZ + c16s * 8;
  const u16* gB0 = Bt + (size_t)(tn + r0) * D_SZ + c16s * 8;
  const u16* gB1 = Bt + (size_t)(tn + 128 + r0) * D_SZ + c16s * 8;

  auto SA = [&](int kt, int kh) {                          // stage A K-half
    u16* d = sm + ((((kt & 1) << 2) | 0 | kh) * 8192) + w * 512;
    const int go = kt * 64 + kh * 32;
    gload_lds16(gA0 + go, d);
    gload_lds16(gA1 + go, d + 4096);
  };
  auto SB = [&](int kt, int kh) {                          // stage B K-half
    u16* d = sm + ((((kt & 1) << 2) | 2 | kh) * 8192) + w * 512;
    const int go = kt * 64 + kh * 32;
    gload_lds16(gB0 + go, d);
    gload_lds16(gB1 + go, d + 4096);
  };

  // ---- read addressing (swizzled, same involution as stage source) ----
  const int fA = (ar & 3) ^ ((ar >> 2) & 3);
  const int sl = (arh ^ fA) * 8;                           // element offset
  const int aoff = (wr * 128 + ar) * 32 + sl;
  const int boff = (wc * 64 + ar) * 32 + sl;

  bf16x8 a0[8], a1[8], b01[2], b23[2];
  auto LDA = [&](bf16x8 (&dst)[8], int buf, int ks) {      // 8 reads
    const u16* base = sm + (((buf << 2) | 0 | ks) * 8192) + aoff;
#pragma unroll
    for (int m = 0; m < 8; m++) dst[m] = *(const bf16x8*)&base[m * 512];
  };
  auto LDB = [&](bf16x8 (&dst)[2], int buf, int ks, int nb) {  // 2 reads
    const u16* base = sm + (((buf << 2) | 2 | ks) * 8192) + boff;
#pragma unroll
    for (int n = 0; n < 2; n++) dst[n] = *(const bf16x8*)&base[(nb + n) * 512];
  };
  auto CL = [&](bf16x8 (&aa)[8], bf16x8 (&bb)[2], int nbase) {  // 16 MFMA
    __builtin_amdgcn_s_setprio(1);
#pragma unroll
    for (int m = 0; m < 8; m++)
#pragma unroll
      for (int n = 0; n < 2; n++)
        acc[m][nbase + n] =
            __builtin_amdgcn_mfma_f32_16x16x32_bf16(aa[m], bb[n], acc[m][nbase + n], 0, 0, 0);
    __builtin_amdgcn_s_setprio(0);
  };

#define BAR() __builtin_amdgcn_s_barrier()
#define LGKM(n) asm volatile("s_waitcnt lgkmcnt(" #n ")" ::: "memory")
#define VMC(n) asm volatile("s_waitcnt vmcnt(" #n ")" ::: "memory")

  // ---- prologue: 7 region-stages (14 loads) ----
  SA(0, 0); SB(0, 0); SA(0, 1); SB(0, 1);   // K-tile 0 complete (8 loads)
  SA(1, 0); SB(1, 0); SA(1, 1);             // K-tile 1 partial
  VMC(6);                                   // tile 0's 4 regions landed
  BAR();
  LDA(a0, 0, 0); LDB(b01, 0, 0, 0);         // prefetch C1(0) operands (10 rd)

  // ---- main loop: K-tiles 0..13 ----
  for (int t = 0; t < 14; ++t) {
    const int buf = t & 1;
    const int nbuf = buf ^ 1;
    // C1: ks0 x n01
    LDB(b23, buf, 0, 2);          // 2 reads for C2
    SB(t + 1, 1);
    LGKM(2);                      // C1's 10 reads done
    CL(a0, b01, 0);
    BAR();
    // C2: ks0 x n23
    LDA(a1, buf, 1); LDB(b01, buf, 1, 0);   // 10 reads for C3
    SA(t + 2, 0);
    LGKM(10);                     // C2's 2 reads done
    CL(a0, b23, 2);
    BAR();
    // C3: ks1 x n01
    LDB(b23, buf, 1, 2);          // 2 reads for C4
    SB(t + 2, 0);
    LGKM(2);                      // C3's 10 reads done
    CL(a1, b01, 0);
    BAR();
    // C4: ks1 x n23  (+ once-per-K-tile vmcnt gate, then prefetch C1(t+1))
    SA(t + 2, 1);
    VMC(6);
    LDA(a0, nbuf, 0); LDB(b01, nbuf, 0, 0); // 10 reads for C1(t+1)
    LGKM(10);                     // C4's 2 reads done
    CL(a1, b23, 2);
    BAR();
  }

  // ---- epilogue K-tile 14 (buf 0) ----
  {
    LDB(b23, 0, 0, 2);
    SB(15, 1);                    // final stage
    LGKM(2);
    CL(a0, b01, 0);
    BAR();
    LDA(a1, 0, 1); LDB(b01, 0, 1, 0);
    LGKM(10);
    CL(a0, b23, 2);
    BAR();
    LDB(b23, 0, 1, 2);
    LGKM(2);
    CL(a1, b01, 0);
    BAR();
    VMC(0);                       // all stages (incl SB(15,1)) landed
    LDA(a0, 1, 0); LDB(b01, 1, 0, 0);
    LGKM(10);
    CL(a1, b23, 2);
    BAR();
  }
  // ---- epilogue K-tile 15 (buf 1): no stages, no barriers needed ----
  {
    LDB(b23, 1, 0, 2);            LGKM(2);  CL(a0, b01, 0);
    LDA(a1, 1, 1); LDB(b01, 1, 1, 0); LGKM(10); CL(a0, b23, 2);
    LDB(b23, 1, 1, 2);            LGKM(2);  CL(a1, b01, 0);
    LGKM(0);                                CL(a1, b23, 2);
  }

  // ---- C-write + hinge loss ----
  float dcs[4];
#pragma unroll
  for (int n = 0; n < 4; n++) dcs[n] = diag[tn + wc * 64 + n * 16 + ar];
  float lsum = 0.f;
#pragma unroll
  for (int m = 0; m < 8; m++) {
#pragma unroll
    for (int i = 0; i < 4; i++) {
      const int r = tm + wr * 128 + m * 16 + arh * 4 + i;
      const float dr = diag[r];
#pragma unroll
      for (int n = 0; n < 4; n++) {
        const int c = tn + wc * 64 + n * 16 + ar;
        const float s_ = acc[m][n][i];
        sim[(size_t)r * B_SZ + c] = s_;
        if (r != c)
          lsum += fmaxf(MARGIN + s_ - dr, 0.f) + fmaxf(MARGIN + s_ - dcs[n], 0.f);
      }
    }
  }
#pragma unroll
  for (int off = 32; off > 0; off >>= 1) lsum += __shfl_down(lsum, off, 64);
  if (l == 0) atomicAdd(loss, lsum);
#undef BAR
#undef LGKM
#undef VMC
}

extern "C" void kernel_launch(void* const* d_in, const int* in_sizes, int n_in,
                              void* d_out, int out_size, void* d_ws, size_t ws_size,
                              hipStream_t stream) {
  const float* im = (const float*)d_in[0];
  const float* tx = (const float*)d_in[1];
  float* out = (float*)d_out;
  float* loss = out;        // output 0: scalar total_loss
  float* sim = out + 1;     // output 1: [4096][4096]

  u16* imn = (u16*)d_ws;
  u16* txn = imn + (size_t)B_SZ * D_SZ;
  float* diag = (float*)(txn + (size_t)B_SZ * D_SZ);

  hipMemsetAsync(d_out, 0, sizeof(float), stream);
  norm_diag_kernel<<<B_SZ, 256, 0, stream>>>(im, tx, imn, txn, diag);
  gemm_loss_kernel<<<(B_SZ / 256) * (B_SZ / 256), 512, 0, stream>>>(imn, txn, diag, sim, loss);
}